// Round 1
// baseline (389.265 us; speedup 1.0000x reference)
//
#include <hip/hip_runtime.h>
#include <hip/hip_bf16.h>

typedef __attribute__((ext_vector_type(8))) __bf16 bf16x8;
typedef __attribute__((ext_vector_type(4))) __bf16 bf16x4;
typedef __attribute__((ext_vector_type(4))) float  f32x4;

#define L_SEQ 200
#define LPAD  208   // 13 tiles of 16 rows

// One block per batch element b.
// Phase 0: per-b effective weights Weff[64][128] -> LDS (B-operand layout, swizzled) + tb[128]
// Phase 1: behavior[b] [200][64] fp32 -> bf16 LDS (swizzled rows)
// Phase 2: MFMA GEMM [200x64]@[64x128], fused relu + W2-dot + lane-reduce -> att[200]
// Phase 3: masked softmax
// Phase 4: weighted sum over the LDS behavior tile -> out[b][64]
__global__ __launch_bounds__(256) void din_attn_kernel(
    const float* __restrict__ behavior,
    const float* __restrict__ target,
    const int*   __restrict__ seqlen,
    const float* __restrict__ W1,
    const float* __restrict__ b1,
    const float* __restrict__ W2,
    float* __restrict__ out)
{
    __shared__ __align__(16) __bf16 Xbf[LPAD * 64];  // [row][e^((row&7)<<3)]
    __shared__ __align__(16) __bf16 Wb[128 * 64];    // [col][k^((col&7)<<3)]
    __shared__ float t_s[64];
    __shared__ float tb_s[128];
    __shared__ float att_s[L_SEQ];
    __shared__ float red_s[8];
    __shared__ float part_s[4 * 64];

    const int b    = blockIdx.x;
    const int tid  = threadIdx.x;
    const int lane = tid & 63;
    const int wave = tid >> 6;

    if (tid < 64) t_s[tid] = target[b * 64 + tid];
    __syncthreads();

    // ---- Phase 0a: Weff[k][col] = W1a + W1d + t[k]*W1c, stored transposed Wb[col][k] (bf16, swizzled)
    {
        const int col = tid & 127;
        const int kh  = tid >> 7;  // 0..1
        #pragma unroll
        for (int kk = 0; kk < 32; ++kk) {
            const int k = kh * 32 + kk;
            float w = W1[k * 128 + col] + W1[(192 + k) * 128 + col]
                    + t_s[k] * W1[(128 + k) * 128 + col];
            Wb[col * 64 + (k ^ ((col & 7) << 3))] = (__bf16)w;
        }
    }
    // ---- Phase 0b: tb[h] = b1[h] + sum_e t[e]*(W1b - W1d)[e][h]   (fp32)
    if (tid < 128) {
        float acc = b1[tid];
        #pragma unroll 4
        for (int e = 0; e < 64; ++e)
            acc += t_s[e] * (W1[(64 + e) * 128 + tid] - W1[(192 + e) * 128 + tid]);
        tb_s[tid] = acc;
    }
    // ---- Phase 1: stage behavior tile -> bf16 LDS (swizzled)
    {
        const float4* Xg = (const float4*)(behavior + (size_t)b * L_SEQ * 64);
        for (int q = tid; q < L_SEQ * 16; q += 256) {
            const int row = q >> 4;
            const int j   = q & 15;
            float4 v = Xg[q];
            const int idx = row * 64 + ((j * 4) ^ ((row & 7) << 3));
            bf16x4 u = { (__bf16)v.x, (__bf16)v.y, (__bf16)v.z, (__bf16)v.w };
            *(bf16x4*)&Xbf[idx] = u;
        }
        for (int q = tid; q < 8 * 64; q += 256) {   // zero-pad rows 200..207
            const int row = L_SEQ + (q >> 6);
            const int e   = q & 63;
            Xbf[row * 64 + (e ^ ((row & 7) << 3))] = (__bf16)0.0f;
        }
    }
    __syncthreads();

    // ---- Phase 2: GEMM + fused relu/W2-dot -> att scores
    {
        bf16x8 bfrag[8][2];
        float tb_l[8], w2_l[8];
        #pragma unroll
        for (int nt = 0; nt < 8; ++nt) {
            const int col = nt * 16 + (lane & 15);
            #pragma unroll
            for (int ks = 0; ks < 2; ++ks) {
                const int k0 = ks * 32 + (lane >> 4) * 8;
                bfrag[nt][ks] = *(const bf16x8*)&Wb[col * 64 + (k0 ^ ((col & 7) << 3))];
            }
            tb_l[nt] = tb_s[col];
            w2_l[nt] = W2[col];
        }
        const f32x4 zero = {0.f, 0.f, 0.f, 0.f};
        for (int tile = wave; tile < 13; tile += 4) {
            const int row = tile * 16 + (lane & 15);
            const int k0  = (lane >> 4) * 8;
            const int sw  = (row & 7) << 3;
            bf16x8 a0 = *(const bf16x8*)&Xbf[row * 64 + (k0 ^ sw)];
            bf16x8 a1 = *(const bf16x8*)&Xbf[row * 64 + ((k0 + 32) ^ sw)];
            f32x4 acc[8];
            #pragma unroll
            for (int nt = 0; nt < 8; ++nt) acc[nt] = zero;
            #pragma unroll
            for (int nt = 0; nt < 8; ++nt) {
                acc[nt] = __builtin_amdgcn_mfma_f32_16x16x32_bf16(a0, bfrag[nt][0], acc[nt], 0, 0, 0);
                acc[nt] = __builtin_amdgcn_mfma_f32_16x16x32_bf16(a1, bfrag[nt][1], acc[nt], 0, 0, 0);
            }
            // h = relu(C + tb); att-partial = h * W2, summed over this lane's 8 cols
            float s[4] = {0.f, 0.f, 0.f, 0.f};
            #pragma unroll
            for (int nt = 0; nt < 8; ++nt) {
                #pragma unroll
                for (int i = 0; i < 4; ++i)
                    s[i] += fmaxf(acc[nt][i] + tb_l[nt], 0.f) * w2_l[nt];
            }
            // reduce across the 16 cols (lanes sharing lane>>4)
            #pragma unroll
            for (int i = 0; i < 4; ++i) {
                float v = s[i];
                v += __shfl_xor(v, 1, 64);
                v += __shfl_xor(v, 2, 64);
                v += __shfl_xor(v, 4, 64);
                v += __shfl_xor(v, 8, 64);
                s[i] = v;
            }
            if ((lane & 15) == 0) {
                const int r = tile * 16 + (lane >> 4) * 4;   // C row = (lane>>4)*4 + i
                #pragma unroll
                for (int i = 0; i < 4; ++i)
                    if (r + i < L_SEQ) att_s[r + i] = s[i];
            }
        }
    }
    __syncthreads();

    // ---- Phase 3: masked softmax over att_s[0..199] (b2 dropped: shift-invariant)
    {
        const int sl = seqlen[b];
        float val = -INFINITY;
        if (tid < L_SEQ) val = (tid < sl) ? att_s[tid] : -1e9f;
        float m = val;
        #pragma unroll
        for (int d = 1; d < 64; d <<= 1) m = fmaxf(m, __shfl_xor(m, d, 64));
        if (lane == 0) red_s[wave] = m;
        __syncthreads();
        m = fmaxf(fmaxf(red_s[0], red_s[1]), fmaxf(red_s[2], red_s[3]));
        float p = (tid < L_SEQ) ? __expf(val - m) : 0.f;
        float sum = p;
        #pragma unroll
        for (int d = 1; d < 64; d <<= 1) sum += __shfl_xor(sum, d, 64);
        if (lane == 0) red_s[4 + wave] = sum;
        __syncthreads();
        sum = red_s[4] + red_s[5] + red_s[6] + red_s[7];
        const float winv = 1.0f / sum;
        if (tid < L_SEQ) att_s[tid] = p * winv;   // reads of att_s all happened before 1st barrier
    }
    __syncthreads();

    // ---- Phase 4: out[e] = sum_l w[l] * X[l][e]
    {
        float acc = 0.f;
        for (int l = wave; l < L_SEQ; l += 4)
            acc += att_s[l] * (float)Xbf[l * 64 + (lane ^ ((l & 7) << 3))];
        part_s[wave * 64 + lane] = acc;
    }
    __syncthreads();
    if (tid < 64)
        out[(size_t)b * 64 + tid] =
            part_s[tid] + part_s[64 + tid] + part_s[128 + tid] + part_s[192 + tid];
}

extern "C" void kernel_launch(void* const* d_in, const int* in_sizes, int n_in,
                              void* d_out, int out_size, void* d_ws, size_t ws_size,
                              hipStream_t stream) {
    (void)n_in; (void)out_size; (void)d_ws; (void)ws_size;
    const float* behavior = (const float*)d_in[0];
    const float* target   = (const float*)d_in[1];
    const int*   seqlen   = (const int*)d_in[2];
    const float* W1       = (const float*)d_in[3];
    const float* b1       = (const float*)d_in[4];
    const float* W2       = (const float*)d_in[5];
    // d_in[6] = b2: unused (softmax shift-invariance; masked entries underflow identically)
    float* out = (float*)d_out;
    const int B = in_sizes[2];   // 4096
    din_attn_kernel<<<dim3(B), dim3(256), 0, stream>>>(behavior, target, seqlen, W1, b1, W2, out);
}

// Round 2
// 334.185 us; speedup vs baseline: 1.1648x; 1.1648x over previous
//
#include <hip/hip_runtime.h>
#include <hip/hip_bf16.h>

typedef __attribute__((ext_vector_type(8))) __bf16 bf16x8;
typedef __attribute__((ext_vector_type(4))) __bf16 bf16x4;
typedef __attribute__((ext_vector_type(4))) float  f32x4;

#define L_SEQ 200
#define LPAD  208   // 13 tiles of 16 rows

// ---------------------------------------------------------------------------
// Setup 1: Bc[128][128] = [[W1a+W1d],[W1c]] in MFMA-B fragment order, bf16.
// Flat layout: ((ct*4+ks)*4 + kq)*128 + c*8 + j   (ct=col-tile, ks=K-chunk/32,
// kq=lane>>4, c=lane&15, j=elem). One element per thread, 64 blocks x 256.
// ---------------------------------------------------------------------------
__global__ void setup_bc(const float* __restrict__ W1, __bf16* __restrict__ Bc) {
    const int idx = blockIdx.x * 256 + threadIdx.x;      // 0..16383
    const int j  = idx & 7;
    const int c  = (idx >> 3) & 15;
    const int kq = (idx >> 7) & 3;
    const int ks = (idx >> 9) & 3;
    const int ct = idx >> 11;
    const int k   = ks * 32 + kq * 8 + j;
    const int col = ct * 16 + c;
    float v;
    if (k < 64) v = W1[k * 128 + col] + W1[(192 + k) * 128 + col];   // W1a + W1d
    else        v = W1[(128 + (k - 64)) * 128 + col];                // W1c
    Bc[idx] = (__bf16)v;
}

// ---------------------------------------------------------------------------
// Setup 2: TB[B][128] = target @ (W1b - W1d) + b1, stored bf16.
// 16 batches per block, Wbd + T staged in LDS.
// ---------------------------------------------------------------------------
__global__ __launch_bounds__(256) void setup_tb(
    const float* __restrict__ target, const float* __restrict__ W1,
    const float* __restrict__ b1, __bf16* __restrict__ TB)
{
    __shared__ float Wbd[64][128];
    __shared__ float Ts[16][64];
    const int tid = threadIdx.x;
    const int b0  = blockIdx.x * 16;
    for (int q = tid; q < 64 * 128; q += 256) {
        const int e = q >> 7, c = q & 127;
        Wbd[e][c] = W1[(64 + e) * 128 + c] - W1[(192 + e) * 128 + c];
    }
    for (int q = tid; q < 16 * 64; q += 256) {
        const int bb = q >> 6, e = q & 63;
        Ts[bb][e] = target[(size_t)(b0 + bb) * 64 + e];
    }
    __syncthreads();
    const int bb = tid >> 4;          // 0..15
    const int c0 = (tid & 15) * 8;    // 0..120
    float acc[8];
    #pragma unroll
    for (int r = 0; r < 8; ++r) acc[r] = b1[c0 + r];
    for (int e = 0; e < 64; ++e) {
        const float tv = Ts[bb][e];
        #pragma unroll
        for (int r = 0; r < 8; ++r) acc[r] += tv * Wbd[e][c0 + r];
    }
    #pragma unroll
    for (int r = 0; r < 8; ++r)
        TB[(size_t)(b0 + bb) * 128 + c0 + r] = (__bf16)acc[r];
}

// ---------------------------------------------------------------------------
// Main: one block per batch. Wave w owns col-tiles {2w, 2w+1}; sweeps all 13
// row-tiles. A = [x | x*t] built in registers (x*t = a_x * t-regs), K=128.
// ---------------------------------------------------------------------------
__global__ __launch_bounds__(256, 4) void din_main(
    const float* __restrict__ behavior,
    const float* __restrict__ target,
    const int*   __restrict__ seqlen,
    const float* __restrict__ W2,
    const __bf16* __restrict__ Bc,
    const __bf16* __restrict__ TB,
    float* __restrict__ out)
{
    __shared__ __align__(16) __bf16 Xbf[LPAD * 64];   // 26624 B, [row][e^((row&7)<<3)]
    __shared__ float att_part[4][LPAD];               //  3328 B
    __shared__ float att_s[LPAD];                     //   832 B
    __shared__ float red_s[8];
    __shared__ float part_s[4 * 64];                  //  1024 B

    const int b    = blockIdx.x;
    const int tid  = threadIdx.x;
    const int lane = tid & 63;
    const int w    = tid >> 6;
    const int kq   = lane >> 4;     // 0..3
    const int c16  = lane & 15;

    // --- B fragments from ws (L2-hot, 16B/lane contiguous per fragment)
    bf16x8 bfrag[2][4];
    #pragma unroll
    for (int i = 0; i < 2; ++i) {
        const int ct = 2 * w + i;
        #pragma unroll
        for (int ks = 0; ks < 4; ++ks)
            bfrag[i][ks] = *(const bf16x8*)(Bc + ((ct * 4 + ks) * 4 + kq) * 128 + c16 * 8);
    }
    // --- t values matching this lane's A-fragment k-positions
    float tf0[8], tf1[8];
    {
        const float* tp = target + (size_t)b * 64 + kq * 8;
        #pragma unroll
        for (int j = 0; j < 8; ++j) { tf0[j] = tp[j]; tf1[j] = tp[32 + j]; }
    }
    float tb_l[2], w2_l[2];
    #pragma unroll
    for (int i = 0; i < 2; ++i) {
        const int col = (2 * w + i) * 16 + c16;
        tb_l[i] = (float)TB[(size_t)b * 128 + col];
        w2_l[i] = W2[col];
    }

    // --- stage behavior -> bf16 LDS (swizzled rows)
    {
        const float4* Xg = (const float4*)(behavior + (size_t)b * L_SEQ * 64);
        for (int q = tid; q < L_SEQ * 16; q += 256) {
            const int row = q >> 4;
            const int j   = q & 15;
            float4 v = Xg[q];
            bf16x4 u = { (__bf16)v.x, (__bf16)v.y, (__bf16)v.z, (__bf16)v.w };
            *(bf16x4*)&Xbf[row * 64 + ((j * 4) ^ ((row & 7) << 3))] = u;
        }
        for (int q = tid; q < 8 * 64; q += 256) {    // zero-pad rows 200..207
            const int row = L_SEQ + (q >> 6);
            const int e   = q & 63;
            Xbf[row * 64 + (e ^ ((row & 7) << 3))] = (__bf16)0.0f;
        }
    }
    __syncthreads();

    // --- GEMM [200x128]@[128x32 per wave] + fused relu/W2-dot
    {
        const int k0 = kq * 8;
        for (int tile = 0; tile < 13; ++tile) {
            const int row = tile * 16 + c16;
            const int sw  = (row & 7) << 3;
            bf16x8 a0 = *(const bf16x8*)&Xbf[row * 64 + (k0 ^ sw)];
            bf16x8 a1 = *(const bf16x8*)&Xbf[row * 64 + ((k0 + 32) ^ sw)];
            bf16x8 a2, a3;
            #pragma unroll
            for (int j = 0; j < 8; ++j) {
                a2[j] = (__bf16)((float)a0[j] * tf0[j]);
                a3[j] = (__bf16)((float)a1[j] * tf1[j]);
            }
            float s[4] = {0.f, 0.f, 0.f, 0.f};
            #pragma unroll
            for (int i = 0; i < 2; ++i) {
                f32x4 acc = {0.f, 0.f, 0.f, 0.f};
                acc = __builtin_amdgcn_mfma_f32_16x16x32_bf16(a0, bfrag[i][0], acc, 0, 0, 0);
                acc = __builtin_amdgcn_mfma_f32_16x16x32_bf16(a1, bfrag[i][1], acc, 0, 0, 0);
                acc = __builtin_amdgcn_mfma_f32_16x16x32_bf16(a2, bfrag[i][2], acc, 0, 0, 0);
                acc = __builtin_amdgcn_mfma_f32_16x16x32_bf16(a3, bfrag[i][3], acc, 0, 0, 0);
                #pragma unroll
                for (int r = 0; r < 4; ++r)
                    s[r] += fmaxf(acc[r] + tb_l[i], 0.f) * w2_l[i];
            }
            #pragma unroll
            for (int r = 0; r < 4; ++r) {          // reduce over the 16 cols
                float v = s[r];
                v += __shfl_xor(v, 1, 64);
                v += __shfl_xor(v, 2, 64);
                v += __shfl_xor(v, 4, 64);
                v += __shfl_xor(v, 8, 64);
                s[r] = v;
            }
            if (c16 == 0) {
                const int r0 = tile * 16 + kq * 4;  // C row = kq*4 + r
                #pragma unroll
                for (int r = 0; r < 4; ++r) att_part[w][r0 + r] = s[r];
            }
        }
    }
    __syncthreads();

    // --- masked softmax (b2 dropped: shift-invariant; all-masked -> uniform)
    {
        const int sl = seqlen[b];
        float val = -INFINITY;
        if (tid < L_SEQ) {
            float v = att_part[0][tid] + att_part[1][tid]
                    + att_part[2][tid] + att_part[3][tid];
            val = (tid < sl) ? v : -1e9f;
        }
        float m = val;
        #pragma unroll
        for (int d = 1; d < 64; d <<= 1) m = fmaxf(m, __shfl_xor(m, d, 64));
        if (lane == 0) red_s[w] = m;
        __syncthreads();
        m = fmaxf(fmaxf(red_s[0], red_s[1]), fmaxf(red_s[2], red_s[3]));
        float p = (tid < L_SEQ) ? __expf(val - m) : 0.f;
        float sum = p;
        #pragma unroll
        for (int d = 1; d < 64; d <<= 1) sum += __shfl_xor(sum, d, 64);
        if (lane == 0) red_s[4 + w] = sum;
        __syncthreads();
        sum = red_s[4] + red_s[5] + red_s[6] + red_s[7];
        const float winv = 1.0f / sum;
        if (tid < L_SEQ) att_s[tid] = p * winv;
    }
    __syncthreads();

    // --- weighted sum: out[e] = sum_l w[l] * X[l][e]
    {
        float acc = 0.f;
        for (int l = w; l < L_SEQ; l += 4)
            acc += att_s[l] * (float)Xbf[l * 64 + (lane ^ ((l & 7) << 3))];
        part_s[w * 64 + lane] = acc;
    }
    __syncthreads();
    if (tid < 64)
        out[(size_t)b * 64 + tid] =
            part_s[tid] + part_s[64 + tid] + part_s[128 + tid] + part_s[192 + tid];
}

extern "C" void kernel_launch(void* const* d_in, const int* in_sizes, int n_in,
                              void* d_out, int out_size, void* d_ws, size_t ws_size,
                              hipStream_t stream) {
    (void)n_in; (void)out_size; (void)ws_size;
    const float* behavior = (const float*)d_in[0];
    const float* target   = (const float*)d_in[1];
    const int*   seqlen   = (const int*)d_in[2];
    const float* W1       = (const float*)d_in[3];
    const float* b1       = (const float*)d_in[4];
    const float* W2       = (const float*)d_in[5];
    // d_in[6] = b2: unused (softmax shift-invariance)
    float* out = (float*)d_out;
    const int B = in_sizes[2];   // 4096

    __bf16* Bc = (__bf16*)d_ws;                       // 32 KB
    __bf16* TB = (__bf16*)((char*)d_ws + 32768);      // B*128*2 = 1 MB

    setup_bc<<<dim3(64), dim3(256), 0, stream>>>(W1, Bc);
    setup_tb<<<dim3(B / 16), dim3(256), 0, stream>>>(target, W1, b1, TB);
    din_main<<<dim3(B), dim3(256), 0, stream>>>(behavior, target, seqlen, W2, Bc, TB, out);
}

// Round 3
// 326.852 us; speedup vs baseline: 1.1910x; 1.0224x over previous
//
#include <hip/hip_runtime.h>
#include <hip/hip_bf16.h>

typedef __attribute__((ext_vector_type(8))) __bf16 bf16x8;
typedef __attribute__((ext_vector_type(4))) __bf16 bf16x4;
typedef __attribute__((ext_vector_type(2))) __bf16 bf16x2;
typedef __attribute__((ext_vector_type(4))) float  f32x4;

#define L_SEQ 200
#define LPAD  208   // 13 tiles of 16 rows

// ---------------------------------------------------------------------------
// Setup 1: Weff[b] = (W1a + W1d) + diag(t_b) @ W1c, bf16, MFMA-B fragment
// order: per batch, frag = ((ct*2+ks)*4+kq)*16+c16 (1024 frags x 8 elems),
// k = ks*32+kq*8+j, col = ct*16+c16. 16 batches/block; W1-derived frags in regs.
// ---------------------------------------------------------------------------
__global__ __launch_bounds__(256) void setup_weff(
    const float* __restrict__ W1, const float* __restrict__ target,
    __bf16* __restrict__ Weff)
{
    __shared__ float t_s[16][64];
    const int tid = threadIdx.x;
    const int b0  = blockIdx.x * 16;
    ((float4*)t_s)[tid] = ((const float4*)(target + (size_t)b0 * 64))[tid];

    // this thread's 4 fragments share (c16,kq,ks) -> same k0; ct = i*2 + (tid>>7)
    const int c16 = tid & 15;
    const int kq  = (tid >> 4) & 3;
    const int ks  = (tid >> 6) & 1;
    const int k0  = ks * 32 + kq * 8;
    float wad[4][8], wc[4][8];
    #pragma unroll
    for (int i = 0; i < 4; ++i) {
        const int col = (i * 2 + (tid >> 7)) * 16 + c16;
        #pragma unroll
        for (int j = 0; j < 8; ++j) {
            const int k = k0 + j;
            wad[i][j] = W1[k * 128 + col] + W1[(192 + k) * 128 + col];
            wc[i][j]  = W1[(128 + k) * 128 + col];
        }
    }
    __syncthreads();
    for (int bb = 0; bb < 16; ++bb) {
        float tv[8];
        #pragma unroll
        for (int j = 0; j < 8; ++j) tv[j] = t_s[bb][k0 + j];
        #pragma unroll
        for (int i = 0; i < 4; ++i) {
            const int frag = i * 256 + tid;
            bf16x8 o;
            #pragma unroll
            for (int j = 0; j < 8; ++j)
                o[j] = (__bf16)(wad[i][j] + tv[j] * wc[i][j]);
            *(bf16x8*)(Weff + ((size_t)(b0 + bb) * 1024 + frag) * 8) = o;
        }
    }
}

// ---------------------------------------------------------------------------
// Setup 2: TB[B][128] = target @ (W1b - W1d) + b1, fp32.
// ---------------------------------------------------------------------------
__global__ __launch_bounds__(256) void setup_tb(
    const float* __restrict__ target, const float* __restrict__ W1,
    const float* __restrict__ b1, float* __restrict__ TB)
{
    __shared__ float Wbd[64][128];
    __shared__ float Ts[16][64];
    const int tid = threadIdx.x;
    const int b0  = blockIdx.x * 16;
    for (int q = tid; q < 64 * 128; q += 256) {
        const int e = q >> 7, c = q & 127;
        Wbd[e][c] = W1[(64 + e) * 128 + c] - W1[(192 + e) * 128 + c];
    }
    ((float4*)Ts)[tid] = ((const float4*)(target + (size_t)b0 * 64))[tid];
    __syncthreads();
    const int bb = tid >> 4;
    const int c0 = (tid & 15) * 8;
    float acc[8];
    #pragma unroll
    for (int r = 0; r < 8; ++r) acc[r] = b1[c0 + r];
    for (int e = 0; e < 64; ++e) {
        const float tv = Ts[bb][e];
        #pragma unroll
        for (int r = 0; r < 8; ++r) acc[r] += tv * Wbd[e][c0 + r];
    }
    #pragma unroll
    for (int r = 0; r < 8; ++r)
        TB[(size_t)(b0 + bb) * 128 + c0 + r] = acc[r];
}

// ---------------------------------------------------------------------------
// Main: one block per batch; wave w owns col-tiles {2w,2w+1}; K=64 (x only).
// ---------------------------------------------------------------------------
__global__ __launch_bounds__(256, 5) void din_main(
    const float* __restrict__ behavior,
    const int*   __restrict__ seqlen,
    const float* __restrict__ W2,
    const __bf16* __restrict__ Weff,
    const float* __restrict__ TB,
    float* __restrict__ out)
{
    __shared__ __align__(16) __bf16 Xbf[LPAD * 64];   // 26624 B
    __shared__ float att_part[4][LPAD];               //  3328 B
    __shared__ float att_s[LPAD];                     //   832 B
    __shared__ float part_s[256];                     //  1024 B
    __shared__ float red_s[8];                        //    32 B  -> 31840 total

    const int b    = blockIdx.x;
    const int tid  = threadIdx.x;
    const int lane = tid & 63;
    const int w    = tid >> 6;
    const int kq   = lane >> 4;
    const int c16  = lane & 15;

    // ---- staging: issue group-A loads first
    const float4* Xg = (const float4*)(behavior + (size_t)b * L_SEQ * 64);
    float4 va[7];
    #pragma unroll
    for (int i = 0; i < 7; ++i) va[i] = Xg[tid + i * 256];

    // independent loads overlap group-A latency: B-frags, tb, w2
    bf16x8 bfrag[2][2];
    float tb_l[2], w2_l[2];
    #pragma unroll
    for (int i = 0; i < 2; ++i) {
        const int ct = 2 * w + i;
        #pragma unroll
        for (int ks = 0; ks < 2; ++ks)
            bfrag[i][ks] = *(const bf16x8*)(Weff +
                ((size_t)b * 1024 + ((ct * 2 + ks) * 4 + kq) * 16 + c16) * 8);
        tb_l[i] = TB[(size_t)b * 128 + ct * 16 + c16];
        w2_l[i] = W2[ct * 16 + c16];
    }
    // group-B loads in flight while we drain group A
    float4 vb[6];
    #pragma unroll
    for (int i = 0; i < 6; ++i) {
        const int q = tid + (7 + i) * 256;
        if (q < L_SEQ * 16) vb[i] = Xg[q];
    }
    #pragma unroll
    for (int i = 0; i < 7; ++i) {
        const int q = tid + i * 256;
        const int row = q >> 4, j4 = (q & 15) * 4, sw = (row & 7) << 3;
        float4 v = va[i];
        bf16x4 u = { (__bf16)v.x, (__bf16)v.y, (__bf16)v.z, (__bf16)v.w };
        *(bf16x4*)&Xbf[row * 64 + (j4 ^ sw)] = u;
    }
    {   // zero-pad rows 200..207 (2 elems/thread)
        const int row = L_SEQ + (tid >> 5), e0 = (tid & 31) * 2;
        bf16x2 z = { (__bf16)0.f, (__bf16)0.f };
        *(bf16x2*)&Xbf[row * 64 + (e0 ^ ((row & 7) << 3))] = z;
    }
    #pragma unroll
    for (int i = 0; i < 6; ++i) {
        const int q = tid + (7 + i) * 256;
        if (q < L_SEQ * 16) {
            const int row = q >> 4, j4 = (q & 15) * 4, sw = (row & 7) << 3;
            float4 v = vb[i];
            bf16x4 u = { (__bf16)v.x, (__bf16)v.y, (__bf16)v.z, (__bf16)v.w };
            *(bf16x4*)&Xbf[row * 64 + (j4 ^ sw)] = u;
        }
    }
    __syncthreads();

    // ---- GEMM (software-pipelined A reads) + fused relu/W2-dot
    {
        const int sw  = (c16 & 7) << 3;           // row&7 == c16&7 for every tile
        const int k0  = kq * 8;
        const int o0  = k0 ^ sw, o1 = (k0 + 32) ^ sw;
        const f32x4 zero = {0.f, 0.f, 0.f, 0.f};
        bf16x8 a0 = *(const bf16x8*)&Xbf[c16 * 64 + o0];
        bf16x8 a1 = *(const bf16x8*)&Xbf[c16 * 64 + o1];
        for (int tile = 0; tile < 13; ++tile) {
            bf16x8 an0, an1;
            if (tile < 12) {
                const int rb = ((tile + 1) * 16 + c16) * 64;
                an0 = *(const bf16x8*)&Xbf[rb + o0];
                an1 = *(const bf16x8*)&Xbf[rb + o1];
            }
            f32x4 acc0 = zero, acc1 = zero;
            acc0 = __builtin_amdgcn_mfma_f32_16x16x32_bf16(a0, bfrag[0][0], acc0, 0, 0, 0);
            acc0 = __builtin_amdgcn_mfma_f32_16x16x32_bf16(a1, bfrag[0][1], acc0, 0, 0, 0);
            acc1 = __builtin_amdgcn_mfma_f32_16x16x32_bf16(a0, bfrag[1][0], acc1, 0, 0, 0);
            acc1 = __builtin_amdgcn_mfma_f32_16x16x32_bf16(a1, bfrag[1][1], acc1, 0, 0, 0);
            float s[4];
            #pragma unroll
            for (int r = 0; r < 4; ++r)
                s[r] = fmaxf(acc0[r] + tb_l[0], 0.f) * w2_l[0]
                     + fmaxf(acc1[r] + tb_l[1], 0.f) * w2_l[1];
            #pragma unroll
            for (int r = 0; r < 4; ++r) {          // reduce over 16 C-cols
                float v = s[r];
                v += __shfl_xor(v, 1, 64);
                v += __shfl_xor(v, 2, 64);
                v += __shfl_xor(v, 4, 64);
                v += __shfl_xor(v, 8, 64);
                s[r] = v;
            }
            if (c16 == 0) {
                const int r0 = tile * 16 + kq * 4;  // C row = kq*4 + r
                #pragma unroll
                for (int r = 0; r < 4; ++r) att_part[w][r0 + r] = s[r];
            }
            a0 = an0; a1 = an1;
        }
    }
    __syncthreads();

    // ---- masked softmax (b2 dropped: shift-invariant; all-masked -> uniform)
    {
        const int sl = seqlen[b];
        float val = -INFINITY;
        if (tid < L_SEQ) {
            float v = att_part[0][tid] + att_part[1][tid]
                    + att_part[2][tid] + att_part[3][tid];
            val = (tid < sl) ? v : -1e9f;
        }
        float m = val;
        #pragma unroll
        for (int d = 1; d < 64; d <<= 1) m = fmaxf(m, __shfl_xor(m, d, 64));
        if (lane == 0) red_s[w] = m;
        __syncthreads();
        m = fmaxf(fmaxf(red_s[0], red_s[1]), fmaxf(red_s[2], red_s[3]));
        float p = (tid < L_SEQ) ? __expf(val - m) : 0.f;
        float sum = p;
        #pragma unroll
        for (int d = 1; d < 64; d <<= 1) sum += __shfl_xor(sum, d, 64);
        if (lane == 0) red_s[4 + w] = sum;
        __syncthreads();
        sum = red_s[4] + red_s[5] + red_s[6] + red_s[7];
        const float winv = 1.0f / sum;
        if (tid < LPAD) att_s[tid] = (tid < L_SEQ) ? p * winv : 0.f;
    }
    __syncthreads();

    // ---- weighted sum: 7 passes of 32 rows x (8 cols/thread), vectorized
    {
        const int prow = tid >> 3;        // 0..31
        const int cg   = tid & 7;         // col-group
        float acc[8] = {0.f,0.f,0.f,0.f,0.f,0.f,0.f,0.f};
        #pragma unroll
        for (int p = 0; p < 7; ++p) {
            const int row = p * 32 + prow;
            if (row < LPAD) {             // only pass 6 partially masked
                const int sw = (row & 7) << 3;
                bf16x8 xv = *(const bf16x8*)&Xbf[row * 64 + ((cg * 8) ^ sw)];
                const float aw = att_s[row];
                #pragma unroll
                for (int j = 0; j < 8; ++j) acc[j] += aw * (float)xv[j];
            }
        }
        #pragma unroll
        for (int j = 0; j < 8; ++j) {     // reduce over the 8 row-owners in wave
            float v = acc[j];
            v += __shfl_xor(v, 8, 64);
            v += __shfl_xor(v, 16, 64);
            v += __shfl_xor(v, 32, 64);
            acc[j] = v;
        }
        if (lane < 8) {                   // lane == cg here
            #pragma unroll
            for (int j = 0; j < 8; ++j) part_s[w * 64 + lane * 8 + j] = acc[j];
        }
    }
    __syncthreads();
    if (tid < 64)
        out[(size_t)b * 64 + tid] =
            part_s[tid] + part_s[64 + tid] + part_s[128 + tid] + part_s[192 + tid];
}

extern "C" void kernel_launch(void* const* d_in, const int* in_sizes, int n_in,
                              void* d_out, int out_size, void* d_ws, size_t ws_size,
                              hipStream_t stream) {
    (void)n_in; (void)out_size; (void)ws_size;
    const float* behavior = (const float*)d_in[0];
    const float* target   = (const float*)d_in[1];
    const int*   seqlen   = (const int*)d_in[2];
    const float* W1       = (const float*)d_in[3];
    const float* b1       = (const float*)d_in[4];
    const float* W2       = (const float*)d_in[5];
    // d_in[6] = b2: unused (softmax shift-invariance)
    float* out = (float*)d_out;
    const int B = in_sizes[2];   // 4096

    __bf16* Weff = (__bf16*)d_ws;                                   // 64 MB
    float*  TB   = (float*)((char*)d_ws + (size_t)B * 8192 * 2);    //  2 MB

    setup_weff<<<dim3(B / 16), dim3(256), 0, stream>>>(W1, target, Weff);
    setup_tb  <<<dim3(B / 16), dim3(256), 0, stream>>>(target, W1, b1, TB);
    din_main  <<<dim3(B), dim3(256), 0, stream>>>(behavior, seqlen, W2, Weff, TB, out);
}